// Round 3
// baseline (702.034 us; speedup 1.0000x reference)
//
#include <hip/hip_runtime.h>
#include <hip/hip_bf16.h>
#include <hip/hip_fp16.h>
#include <cstdint>

typedef __bf16 bf16x8 __attribute__((ext_vector_type(8)));
typedef unsigned short ushortx8 __attribute__((ext_vector_type(8)));
typedef unsigned short ushortx4 __attribute__((ext_vector_type(4)));
typedef float f32x4 __attribute__((ext_vector_type(4)));

constexpr int Cc  = 512;       // channels
constexpr int Ssp = 3136;      // 56*56 spatial per image
constexpr float NINV = 1.f / 100352.f;   // 1/(32*3136)

__device__ __forceinline__ unsigned short f2bf(float f) {
    union { float f; unsigned u; } a; a.f = f;
    unsigned u = a.u;
    unsigned r = u + 0x7fffu + ((u >> 16) & 1u);   // RNE
    return (unsigned short)(r >> 16);
}
__device__ __forceinline__ float bf2f(unsigned short h) {
    union { unsigned u; float f; } a; a.u = ((unsigned)h) << 16;
    return a.f;
}
__device__ __forceinline__ unsigned short f2h(float f) {
    _Float16 h = (_Float16)f;
    return __builtin_bit_cast(unsigned short, h);
}
__device__ __forceinline__ float h2f(unsigned short u) {
    return (float)__builtin_bit_cast(_Float16, u);
}
__device__ __forceinline__ float tanh_fast(float u) {
    float e = __expf(2.f * u);
    return 1.f - 2.f / (e + 1.f);
}
__device__ __forceinline__ int swz(int row, int k) {
    return k ^ (((row >> 2) & 7) << 3);
}

// ---------------- K0: fc_w fp32 -> bf16 ----------------
__global__ void kWconv(const float* __restrict__ w, unsigned short* __restrict__ wb) {
    int i = (blockIdx.x * 256 + threadIdx.x) * 4;
    float4 v = *(const float4*)(w + i);
    ushortx4 o;
    o[0] = f2bf(v.x); o[1] = f2bf(v.y); o[2] = f2bf(v.z); o[3] = f2bf(v.w);
    *(ushortx4*)(wb + i) = o;
}

// ---------------- KA: GEMM(+residual+bias) fused with Gram+tanh+stats ----------------
__global__ __launch_bounds__(512, 4) void kA(
    const float* __restrict__ x, const unsigned short* __restrict__ wb,
    const float* __restrict__ fcb, unsigned short* __restrict__ sb16,
    float* __restrict__ gstats)
{
    __shared__ __attribute__((aligned(16))) unsigned short xl[64 * 72];   // [s][k] bf16 / later [pq][n] fp16
    __shared__ __attribute__((aligned(16))) unsigned short tl[64 * 520];  // [s][c] bf16, pitch 520
    __shared__ float statsl[512];

    const int tid  = threadIdx.x;
    const int wave = tid >> 6;
    const int lane = tid & 63;
    const int lg   = lane >> 4;
    const int lm   = lane & 15;

    const int blk = blockIdx.x;
    const int b   = blk / 49;
    const int sc  = blk % 49;
    const float* xA = x + (size_t)b * Cc * Ssp + sc * 64;   // + k*3136 + s

    f32x4 acc[4][4];
#pragma unroll
    for (int mi = 0; mi < 4; ++mi)
#pragma unroll
        for (int ni = 0; ni < 4; ++ni) acc[mi][ni] = (f32x4){0.f, 0.f, 0.f, 0.f};

    float bias[4];
#pragma unroll
    for (int ni = 0; ni < 4; ++ni) bias[ni] = fcb[wave * 64 + ni * 16 + lm];

    const int stid = tid >> 4;         // 0..31 (k-row within half-tile)
    const int s4   = (tid & 15) * 4;   // s quad

    // ---- prefetch x tile 0 into registers ----
    float4 xv0 = *(const float4*)(xA + (size_t)stid * Ssp + s4);
    float4 xv1 = *(const float4*)(xA + (size_t)(stid + 32) * Ssp + s4);

#pragma unroll
    for (int kt = 0; kt < 8; ++kt) {
        __builtin_amdgcn_s_barrier();               // xl free (prev readers done)
        // ---- stage prefetched regs -> LDS [s][k] bf16 (transposed) ----
#pragma unroll
        for (int i = 0; i < 4; ++i) {
            int row = s4 + i;
            xl[row * 72 + swz(row, stid)]      = f2bf(((const float*)&xv0)[i]);
            xl[row * 72 + swz(row, stid + 32)] = f2bf(((const float*)&xv1)[i]);
        }
        // ---- issue next-tile x loads (stay in flight across barrier) ----
        if (kt < 7) {
            xv0 = *(const float4*)(xA + (size_t)((kt + 1) * 64 + stid) * Ssp + s4);
            xv1 = *(const float4*)(xA + (size_t)((kt + 1) * 64 + stid + 32) * Ssp + s4);
        }
        // ---- issue this tile's weight fragments (L2-resident) ----
        bf16x8 wv[8];
#pragma unroll
        for (int ks = 0; ks < 2; ++ks)
#pragma unroll
            for (int ni = 0; ni < 4; ++ni) {
                int c = wave * 64 + ni * 16 + lm;
                wv[ks * 4 + ni] = *(const bf16x8*)(wb + (size_t)c * 512 + kt * 64 + ks * 32 + 8 * lg);
            }
        asm volatile("s_waitcnt lgkmcnt(0)" ::: "memory");   // ds_writes visible
        __builtin_amdgcn_s_barrier();

        // ---- residual add: wave kt owns c-range == this tile's k-range ----
        if (wave == kt) {
#pragma unroll
            for (int mi = 0; mi < 4; ++mi)
#pragma unroll
                for (int ni = 0; ni < 4; ++ni) {
                    int kl = ni * 16 + lm;
#pragma unroll
                    for (int j = 0; j < 4; ++j) {
                        int row = mi * 16 + lg * 4 + j;
                        acc[mi][ni][j] += bf2f(xl[row * 72 + swz(row, kl)]);
                    }
                }
        }

        // ---- MFMA: 2 k-steps of 32 ----
#pragma unroll
        for (int ks = 0; ks < 2; ++ks) {
#pragma unroll
            for (int mi = 0; mi < 4; ++mi) {
                int row = mi * 16 + lm;
                bf16x8 af = *(const bf16x8*)&xl[row * 72 + swz(row, ks * 32 + 8 * lg)];
#pragma unroll
                for (int ni = 0; ni < 4; ++ni)
                    acc[mi][ni] = __builtin_amdgcn_mfma_f32_16x16x32_bf16(
                        af, wv[ks * 4 + ni], acc[mi][ni], 0, 0, 0);
            }
        }
    }

    // ---- epilogue: t = acc + bias -> LDS [s][c] bf16 ----
#pragma unroll
    for (int mi = 0; mi < 4; ++mi)
#pragma unroll
        for (int ni = 0; ni < 4; ++ni) {
            int c = wave * 64 + ni * 16 + lm;
#pragma unroll
            for (int j = 0; j < 4; ++j) {
                int srow = mi * 16 + lg * 4 + j;
                tl[srow * 520 + c] = f2bf(acc[mi][ni][j] + bias[ni]);
            }
        }
    statsl[tid] = 0.f;
    __syncthreads();

    // ---- phase 2: per-n Gram via mfma(f, f, 0); identical A/B frags => layout-safe ----
    float sum[4] = {0, 0, 0, 0}, ssq[4] = {0, 0, 0, 0};
    unsigned svp[8][2];                     // packed fp16 s-values [nn][j-pair]
    for (int nn = 0; nn < 8; ++nn) {
        int nl = wave * 8 + nn;
        ushortx8 uf;
#pragma unroll
        for (int bs = 0; bs < 8; ++bs) {
            int cidx = (bs * 4 + lg) * 16 + lm;
            uf[bs] = tl[nl * 520 + cidx];
        }
        bf16x8 f = __builtin_bit_cast(bf16x8, uf);
        f32x4 d = __builtin_amdgcn_mfma_f32_16x16x32_bf16(f, f, (f32x4){0, 0, 0, 0}, 0, 0, 0);
        unsigned short h[4];
#pragma unroll
        for (int j = 0; j < 4; ++j) {
            float sv = tanh_fast(d[j] * (1.f / 32.f));
            sum[j] += sv; ssq[j] += sv * sv;
            h[j] = f2h(sv);
        }
        svp[nn][0] = (unsigned)h[0] | ((unsigned)h[1] << 16);
        svp[nn][1] = (unsigned)h[2] | ((unsigned)h[3] << 16);
    }
#pragma unroll
    for (int j = 0; j < 4; ++j) {
        int pq = (lg * 4 + j) * 16 + lm;
        atomicAdd(&statsl[pq], sum[j]);
        atomicAdd(&statsl[256 + pq], ssq[j]);
    }
    __syncthreads();
    if (tid < 256) {
        atomicAdd(&gstats[tid], statsl[tid]);
        atomicAdd(&gstats[256 + tid], statsl[256 + tid]);
    }

    // ---- phase 3: transpose s through xl -> sb16[pq][n] fp16, coalesced ----
    const size_t nbase = (size_t)b * Ssp + sc * 64;
#pragma unroll
    for (int ci = 0; ci < 4; ++ci) {        // pq chunk ci*64 .. ci*64+63
        __syncthreads();                    // xl free
        if (lg == ci) {
#pragma unroll
            for (int nn = 0; nn < 8; ++nn)
#pragma unroll
                for (int j = 0; j < 4; ++j) {
                    unsigned short hv = (unsigned short)(svp[nn][j >> 1] >> (16 * (j & 1)));
                    xl[(j * 16 + lm) * 72 + wave * 8 + nn] = hv;   // [pq_local][n_local]
                }
        }
        __syncthreads();
        int pql = tid >> 3;                 // 0..63
        int n8  = (tid & 7) * 8;            // 0..56
        ushortx8 v = *(const ushortx8*)&xl[pql * 72 + n8];
        *(ushortx8*)(sb16 + (size_t)(ci * 64 + pql) * 100352 + nbase + n8) = v;
    }
}

// ---------------- KB: finalize BN stats ----------------
__global__ void kB(const float* __restrict__ gstats, float* __restrict__ minv) {
    int t = threadIdx.x;
    float mean = gstats[t] * NINV;
    float var  = gstats[256 + t] * NINV - mean * mean;   // biased var
    minv[t]       = mean;
    minv[256 + t] = rsqrtf(var + 1e-5f);
}

// ---------------- KC: out = x + BN(s)[c>>1], pure stream, no LDS ----------------
__global__ __launch_bounds__(256) void kC(
    const float* __restrict__ x, const unsigned short* __restrict__ sb16,
    const float* __restrict__ minv, const float* __restrict__ gamma,
    const float* __restrict__ beta, float* __restrict__ out)
{
    const int bc = blockIdx.x;              // 0..16383 = b*512 + c
    const int b = bc >> 9, c = bc & 511;
    const int pq = c >> 1;
    const float m = minv[pq], inv = minv[256 + pq];
    const float ga = gamma[c] * inv;
    const float be = beta[c] - m * ga;
    const float* xb = x + ((size_t)b * Cc + c) * Ssp;
    float* ob = out + ((size_t)b * Cc + c) * Ssp;
    const unsigned short* sr = sb16 + (size_t)pq * 100352 + (size_t)b * Ssp;
    const int t = threadIdx.x;
#pragma unroll
    for (int i = 0; i < 4; ++i) {
        int idx = i * 256 + t;              // float4 index, 784 per row
        if (idx < 784) {
            float4 xv = *(const float4*)(xb + idx * 4);
            ushortx4 sv = *(const ushortx4*)(sr + idx * 4);
            float4 r;
            r.x = xv.x + h2f(sv[0]) * ga + be;
            r.y = xv.y + h2f(sv[1]) * ga + be;
            r.z = xv.z + h2f(sv[2]) * ga + be;
            r.w = xv.w + h2f(sv[3]) * ga + be;
            *(float4*)(ob + idx * 4) = r;
        }
    }
}

extern "C" void kernel_launch(void* const* d_in, const int* in_sizes, int n_in,
                              void* d_out, int out_size, void* d_ws, size_t ws_size,
                              hipStream_t stream) {
    const float* x     = (const float*)d_in[0];
    const float* fcw   = (const float*)d_in[1];
    const float* fcb   = (const float*)d_in[2];
    const float* gamma = (const float*)d_in[3];
    const float* beta  = (const float*)d_in[4];
    float* out = (float*)d_out;

    char* ws = (char*)d_ws;
    unsigned short* wb = (unsigned short*)ws;                  // 512 KB bf16 weights
    float* gstats = (float*)(ws + 512 * 512 * 2);              // 512 floats (sum, sumsq)
    float* minv   = (float*)(ws + 512 * 512 * 2 + 2048);       // 512 floats (mean, inv)
    unsigned short* sb16 = (unsigned short*)(ws + (1 << 20));  // [256 pq][100352 n] fp16 (~51 MB)

    hipMemsetAsync(gstats, 0, 2048, stream);
    kWconv<<<dim3(256), dim3(256), 0, stream>>>(fcw, wb);
    kA<<<dim3(1568), dim3(512), 0, stream>>>(x, wb, fcb, sb16, gstats);
    kB<<<dim3(1), dim3(256), 0, stream>>>(gstats, minv);
    kC<<<dim3(16384), dim3(256), 0, stream>>>(x, sb16, minv, gamma, beta, out);
}

// Round 4
// 597.475 us; speedup vs baseline: 1.1750x; 1.1750x over previous
//
#include <hip/hip_runtime.h>
#include <hip/hip_bf16.h>
#include <hip/hip_fp16.h>
#include <cstdint>

typedef __bf16 bf16x8 __attribute__((ext_vector_type(8)));
typedef unsigned short ushortx8 __attribute__((ext_vector_type(8)));
typedef unsigned short ushortx4 __attribute__((ext_vector_type(4)));
typedef float f32x4 __attribute__((ext_vector_type(4)));

constexpr int Cc  = 512;       // channels
constexpr int Ssp = 3136;      // 56*56 spatial per image
constexpr float NINV = 1.f / 100352.f;   // 1/(32*3136)

__device__ __forceinline__ unsigned short f2bf(float f) {
    union { float f; unsigned u; } a; a.f = f;
    unsigned u = a.u;
    unsigned r = u + 0x7fffu + ((u >> 16) & 1u);   // RNE
    return (unsigned short)(r >> 16);
}
__device__ __forceinline__ float bf2f(unsigned short h) {
    union { unsigned u; float f; } a; a.u = ((unsigned)h) << 16;
    return a.f;
}
__device__ __forceinline__ unsigned short f2h(float f) {
    _Float16 h = (_Float16)f;
    return __builtin_bit_cast(unsigned short, h);
}
__device__ __forceinline__ float h2f(unsigned short u) {
    return (float)__builtin_bit_cast(_Float16, u);
}
__device__ __forceinline__ float tanh_fast(float u) {
    float e = __expf(2.f * u);
    return 1.f - 2.f / (e + 1.f);
}
__device__ __forceinline__ int swz(int row, int k) {
    return k ^ (((row >> 2) & 7) << 3);
}

// ---------------- K0: fc_w fp32 -> bf16 ----------------
__global__ void kWconv(const float* __restrict__ w, unsigned short* __restrict__ wb) {
    int i = (blockIdx.x * 256 + threadIdx.x) * 4;
    float4 v = *(const float4*)(w + i);
    ushortx4 o;
    o[0] = f2bf(v.x); o[1] = f2bf(v.y); o[2] = f2bf(v.z); o[3] = f2bf(v.w);
    *(ushortx4*)(wb + i) = o;
}

// ---------------- KA: GEMM(+residual+bias) fused with Gram+tanh+stats ----------------
// launch_bounds(512,2): reg cap 256/lane -> acc[4][4] AGPRs + wv[8] + x-prefetch fit
// with NO scratch spill (round-3's (512,4) cap=128 spilled ~250MB/launch).
__global__ __launch_bounds__(512, 2) void kA(
    const float* __restrict__ x, const unsigned short* __restrict__ wb,
    const float* __restrict__ fcb, unsigned short* __restrict__ sb16,
    float* __restrict__ gstats)
{
    __shared__ __attribute__((aligned(16))) unsigned short xl[64 * 72];   // [s][k] bf16 / later [pq][n] fp16
    __shared__ __attribute__((aligned(16))) unsigned short tl[64 * 520];  // [s][c] bf16, pitch 520
    __shared__ float statsl[512];

    const int tid  = threadIdx.x;
    const int wave = tid >> 6;
    const int lane = tid & 63;
    const int lg   = lane >> 4;
    const int lm   = lane & 15;

    const int blk = blockIdx.x;
    const int b   = blk / 49;
    const int sc  = blk % 49;
    const float* xA = x + (size_t)b * Cc * Ssp + sc * 64;   // + k*3136 + s

    f32x4 acc[4][4];
#pragma unroll
    for (int mi = 0; mi < 4; ++mi)
#pragma unroll
        for (int ni = 0; ni < 4; ++ni) acc[mi][ni] = (f32x4){0.f, 0.f, 0.f, 0.f};

    float bias[4];
#pragma unroll
    for (int ni = 0; ni < 4; ++ni) bias[ni] = fcb[wave * 64 + ni * 16 + lm];

    const int stid = tid >> 4;         // 0..31 (k-row within half-tile)
    const int s4   = (tid & 15) * 4;   // s quad

    // ---- prefetch x tile 0 into registers ----
    float4 xv0 = *(const float4*)(xA + (size_t)stid * Ssp + s4);
    float4 xv1 = *(const float4*)(xA + (size_t)(stid + 32) * Ssp + s4);

#pragma unroll
    for (int kt = 0; kt < 8; ++kt) {
        __builtin_amdgcn_s_barrier();               // xl free (prev readers done)
        // ---- stage prefetched regs -> LDS [s][k] bf16 (transposed) ----
#pragma unroll
        for (int i = 0; i < 4; ++i) {
            int row = s4 + i;
            xl[row * 72 + swz(row, stid)]      = f2bf(((const float*)&xv0)[i]);
            xl[row * 72 + swz(row, stid + 32)] = f2bf(((const float*)&xv1)[i]);
        }
        // ---- issue next-tile x loads (stay in flight across barrier) ----
        if (kt < 7) {
            xv0 = *(const float4*)(xA + (size_t)((kt + 1) * 64 + stid) * Ssp + s4);
            xv1 = *(const float4*)(xA + (size_t)((kt + 1) * 64 + stid + 32) * Ssp + s4);
        }
        // ---- issue this tile's weight fragments (L2-resident) ----
        bf16x8 wv[8];
#pragma unroll
        for (int ks = 0; ks < 2; ++ks)
#pragma unroll
            for (int ni = 0; ni < 4; ++ni) {
                int c = wave * 64 + ni * 16 + lm;
                wv[ks * 4 + ni] = *(const bf16x8*)(wb + (size_t)c * 512 + kt * 64 + ks * 32 + 8 * lg);
            }
        asm volatile("s_waitcnt lgkmcnt(0)" ::: "memory");   // ds_writes visible
        __builtin_amdgcn_s_barrier();

        // ---- residual add: wave kt owns c-range == this tile's k-range ----
        if (wave == kt) {
#pragma unroll
            for (int mi = 0; mi < 4; ++mi)
#pragma unroll
                for (int ni = 0; ni < 4; ++ni) {
                    int kl = ni * 16 + lm;
#pragma unroll
                    for (int j = 0; j < 4; ++j) {
                        int row = mi * 16 + lg * 4 + j;
                        acc[mi][ni][j] += bf2f(xl[row * 72 + swz(row, kl)]);
                    }
                }
        }

        // ---- MFMA: 2 k-steps of 32 ----
#pragma unroll
        for (int ks = 0; ks < 2; ++ks) {
#pragma unroll
            for (int mi = 0; mi < 4; ++mi) {
                int row = mi * 16 + lm;
                bf16x8 af = *(const bf16x8*)&xl[row * 72 + swz(row, ks * 32 + 8 * lg)];
#pragma unroll
                for (int ni = 0; ni < 4; ++ni)
                    acc[mi][ni] = __builtin_amdgcn_mfma_f32_16x16x32_bf16(
                        af, wv[ks * 4 + ni], acc[mi][ni], 0, 0, 0);
            }
        }
    }

    // ---- epilogue: t = acc + bias -> LDS [s][c] bf16 ----
#pragma unroll
    for (int mi = 0; mi < 4; ++mi)
#pragma unroll
        for (int ni = 0; ni < 4; ++ni) {
            int c = wave * 64 + ni * 16 + lm;
#pragma unroll
            for (int j = 0; j < 4; ++j) {
                int srow = mi * 16 + lg * 4 + j;
                tl[srow * 520 + c] = f2bf(acc[mi][ni][j] + bias[ni]);
            }
        }
    statsl[tid] = 0.f;
    __syncthreads();

    // ---- phase 2: per-n Gram via mfma(f, f, 0); identical A/B frags => layout-safe ----
    float sum[4] = {0, 0, 0, 0}, ssq[4] = {0, 0, 0, 0};
    unsigned svp[8][2];                     // packed fp16 s-values [nn][j-pair]
    for (int nn = 0; nn < 8; ++nn) {
        int nl = wave * 8 + nn;
        ushortx8 uf;
#pragma unroll
        for (int bs = 0; bs < 8; ++bs) {
            int cidx = (bs * 4 + lg) * 16 + lm;
            uf[bs] = tl[nl * 520 + cidx];
        }
        bf16x8 f = __builtin_bit_cast(bf16x8, uf);
        f32x4 d = __builtin_amdgcn_mfma_f32_16x16x32_bf16(f, f, (f32x4){0, 0, 0, 0}, 0, 0, 0);
        unsigned short h[4];
#pragma unroll
        for (int j = 0; j < 4; ++j) {
            float sv = tanh_fast(d[j] * (1.f / 32.f));
            sum[j] += sv; ssq[j] += sv * sv;
            h[j] = f2h(sv);
        }
        svp[nn][0] = (unsigned)h[0] | ((unsigned)h[1] << 16);
        svp[nn][1] = (unsigned)h[2] | ((unsigned)h[3] << 16);
    }
#pragma unroll
    for (int j = 0; j < 4; ++j) {
        int pq = (lg * 4 + j) * 16 + lm;
        atomicAdd(&statsl[pq], sum[j]);
        atomicAdd(&statsl[256 + pq], ssq[j]);
    }
    __syncthreads();
    if (tid < 256) {
        atomicAdd(&gstats[tid], statsl[tid]);
        atomicAdd(&gstats[256 + tid], statsl[256 + tid]);
    }

    // ---- phase 3: transpose s through xl -> sb16[pq][n] fp16, coalesced ----
    const size_t nbase = (size_t)b * Ssp + sc * 64;
#pragma unroll
    for (int ci = 0; ci < 4; ++ci) {        // pq chunk ci*64 .. ci*64+63
        __syncthreads();                    // xl free
        if (lg == ci) {
#pragma unroll
            for (int nn = 0; nn < 8; ++nn)
#pragma unroll
                for (int j = 0; j < 4; ++j) {
                    unsigned short hv = (unsigned short)(svp[nn][j >> 1] >> (16 * (j & 1)));
                    xl[(j * 16 + lm) * 72 + wave * 8 + nn] = hv;   // [pq_local][n_local]
                }
        }
        __syncthreads();
        int pql = tid >> 3;                 // 0..63
        int n8  = (tid & 7) * 8;            // 0..56
        ushortx8 v = *(const ushortx8*)&xl[pql * 72 + n8];
        *(ushortx8*)(sb16 + (size_t)(ci * 64 + pql) * 100352 + nbase + n8) = v;
    }
}

// ---------------- KB: finalize BN stats ----------------
__global__ void kB(const float* __restrict__ gstats, float* __restrict__ minv) {
    int t = threadIdx.x;
    float mean = gstats[t] * NINV;
    float var  = gstats[256 + t] * NINV - mean * mean;   // biased var
    minv[t]       = mean;
    minv[256 + t] = rsqrtf(var + 1e-5f);
}

// ---------------- KC: out = x + BN(s)[c>>1], pure stream, no LDS ----------------
__global__ __launch_bounds__(256) void kC(
    const float* __restrict__ x, const unsigned short* __restrict__ sb16,
    const float* __restrict__ minv, const float* __restrict__ gamma,
    const float* __restrict__ beta, float* __restrict__ out)
{
    const int bc = blockIdx.x;              // 0..16383 = b*512 + c
    const int b = bc >> 9, c = bc & 511;
    const int pq = c >> 1;
    const float m = minv[pq], inv = minv[256 + pq];
    const float ga = gamma[c] * inv;
    const float be = beta[c] - m * ga;
    const float* xb = x + ((size_t)b * Cc + c) * Ssp;
    float* ob = out + ((size_t)b * Cc + c) * Ssp;
    const unsigned short* sr = sb16 + (size_t)pq * 100352 + (size_t)b * Ssp;
    const int t = threadIdx.x;
#pragma unroll
    for (int i = 0; i < 4; ++i) {
        int idx = i * 256 + t;              // float4 index, 784 per row
        if (idx < 784) {
            float4 xv = *(const float4*)(xb + idx * 4);
            ushortx4 sv = *(const ushortx4*)(sr + idx * 4);
            float4 r;
            r.x = xv.x + h2f(sv[0]) * ga + be;
            r.y = xv.y + h2f(sv[1]) * ga + be;
            r.z = xv.z + h2f(sv[2]) * ga + be;
            r.w = xv.w + h2f(sv[3]) * ga + be;
            *(float4*)(ob + idx * 4) = r;
        }
    }
}

extern "C" void kernel_launch(void* const* d_in, const int* in_sizes, int n_in,
                              void* d_out, int out_size, void* d_ws, size_t ws_size,
                              hipStream_t stream) {
    const float* x     = (const float*)d_in[0];
    const float* fcw   = (const float*)d_in[1];
    const float* fcb   = (const float*)d_in[2];
    const float* gamma = (const float*)d_in[3];
    const float* beta  = (const float*)d_in[4];
    float* out = (float*)d_out;

    char* ws = (char*)d_ws;
    unsigned short* wb = (unsigned short*)ws;                  // 512 KB bf16 weights
    float* gstats = (float*)(ws + 512 * 512 * 2);              // 512 floats (sum, sumsq)
    float* minv   = (float*)(ws + 512 * 512 * 2 + 2048);       // 512 floats (mean, inv)
    unsigned short* sb16 = (unsigned short*)(ws + (1 << 20));  // [256 pq][100352 n] fp16 (~51 MB)

    hipMemsetAsync(gstats, 0, 2048, stream);
    kWconv<<<dim3(256), dim3(256), 0, stream>>>(fcw, wb);
    kA<<<dim3(1568), dim3(512), 0, stream>>>(x, wb, fcb, sb16, gstats);
    kB<<<dim3(1), dim3(256), 0, stream>>>(gstats, minv);
    kC<<<dim3(16384), dim3(256), 0, stream>>>(x, sb16, minv, gamma, beta, out);
}